// Round 1
// baseline (3452.701 us; speedup 1.0000x reference)
//
#include <hip/hip_runtime.h>
#include <math.h>

#define N_NODES 50000
#define N_EDGES 800000
#define FE 32
#define H 128
#define GRAPHS 64

__device__ inline unsigned encf(float f){
  unsigned u = __float_as_uint(f);
  return (u & 0x80000000u) ? ~u : (u | 0x80000000u);
}
__device__ inline float decf(unsigned u){
  unsigned b = (u & 0x80000000u) ? (u & 0x7fffffffu) : ~u;
  return __uint_as_float(b);
}

// ---- degree count (edges only; +2 self-loops folded into dinv) ----
__global__ __launch_bounds__(256) void k_deg(const int* __restrict__ col, float* __restrict__ cnt){
  int e = blockIdx.x*256 + threadIdx.x;
  if(e < N_EDGES) atomicAdd(&cnt[col[e]], 1.0f);
}

__global__ __launch_bounds__(256) void k_dinv(const float* __restrict__ cnt, float* __restrict__ dinv){
  int i = blockIdx.x*256 + threadIdx.x;
  if(i < N_NODES) dinv[i] = rsqrtf(cnt[i] + 2.0f);
}

// ---- GEMM: out[M,128] = A[M,128] @ W[128,128]; mode 1: out = acc + addC + avec⊗bias ----
__global__ __launch_bounds__(256) void k_gemm(const float* __restrict__ A,
    const float* __restrict__ W, float* __restrict__ out,
    const float* __restrict__ addC, const float* __restrict__ avec,
    const float* __restrict__ bias, int M, int mode){
  __shared__ float As[32][33];
  __shared__ float Ws[32][128];
  int tid = threadIdx.x;
  int tx = tid & 127, ty = tid >> 7;
  int rowBase = blockIdx.x * 32;
  float acc[16];
  #pragma unroll
  for(int i=0;i<16;i++) acc[i]=0.f;
  for(int kc=0;kc<4;kc++){
    #pragma unroll
    for(int p=0;p<4;p++){
      int q = tid + p*256;
      int r = q >> 5, c = q & 31;
      int gr = rowBase + r;
      As[r][c] = (gr < M) ? A[gr*128 + kc*32 + c] : 0.f;
    }
    #pragma unroll
    for(int p=0;p<16;p++){
      int q = tid + p*256;
      int r = q >> 7, c = q & 127;
      Ws[r][c] = W[(kc*32+r)*128 + c];
    }
    __syncthreads();
    #pragma unroll
    for(int kk=0;kk<32;kk++){
      float w = Ws[kk][tx];
      #pragma unroll
      for(int rr=0;rr<16;rr++)
        acc[rr] += As[rr*2+ty][kk] * w;
    }
    __syncthreads();
  }
  #pragma unroll
  for(int rr=0;rr<16;rr++){
    int gr = rowBase + rr*2+ty;
    if(gr < M){
      float v = acc[rr];
      if(mode==1) v += addC[gr*128+tx] + avec[gr]*bias[tx];
      out[gr*128+tx] = v;
    }
  }
}

// ---- conv scatter: accum[col] += dinv[row]*dinv[col] * xw[row]  (one wave per edge) ----
__global__ __launch_bounds__(256) void k_conv(const int* __restrict__ row,
    const int* __restrict__ col, const float* __restrict__ dinv,
    const float* __restrict__ xw, float* __restrict__ accum){
  int lane = threadIdx.x & 63;
  int wid = threadIdx.x >> 6;
  int e = blockIdx.x*4 + wid;
  if(e >= N_EDGES) return;
  int r = row[e], c = col[e];
  float norm = dinv[r]*dinv[c];
  float2 v = *(const float2*)&xw[r*128 + lane*2];
  atomicAdd(&accum[c*128 + lane*2],   v.x*norm);
  atomicAdd(&accum[c*128 + lane*2+1], v.y*norm);
}

// ---- h = elu(accum + 2*dinv^2*xw + b); s1 = h@Watt[:H], s2 = h@Watt[H:] ----
__global__ __launch_bounds__(256) void k_elu_score(const float* __restrict__ accum,
    const float* __restrict__ xw, const float* __restrict__ dinv,
    const float* __restrict__ b, const float* __restrict__ Watt,
    float* __restrict__ h, float* __restrict__ s1, float* __restrict__ s2){
  int lane = threadIdx.x & 63;
  int wid = threadIdx.x >> 6;
  int i = blockIdx.x*4 + wid;
  if(i >= N_NODES) return;
  float di = dinv[i]; float sl = 2.f*di*di;
  float2 a  = *(const float2*)&accum[i*128+lane*2];
  float2 xv = *(const float2*)&xw[i*128+lane*2];
  float2 bb = *(const float2*)&b[lane*2];
  float x0 = a.x + sl*xv.x + bb.x;
  float x1 = a.y + sl*xv.y + bb.y;
  float h0 = x0 > 0.f ? x0 : expm1f(x0);
  float h1 = x1 > 0.f ? x1 : expm1f(x1);
  *(float2*)&h[i*128+lane*2] = make_float2(h0,h1);
  float2 w1 = *(const float2*)&Watt[lane*2];
  float2 w2 = *(const float2*)&Watt[128+lane*2];
  float p1 = h0*w1.x + h1*w1.y;
  float p2 = h0*w2.x + h1*w2.y;
  #pragma unroll
  for(int off=32; off; off>>=1){
    p1 += __shfl_down(p1, off);
    p2 += __shfl_down(p2, off);
  }
  if(lane==0){ s1[i]=p1; s2[i]=p2; }
}

// ---- max reduction of s1,s2 into encoded uints ----
__global__ __launch_bounds__(256) void k_maxred(const float* __restrict__ s1,
    const float* __restrict__ s2, unsigned* __restrict__ scalU){
  float m1 = -1e38f, m2 = -1e38f;
  for(int i = blockIdx.x*256+threadIdx.x; i < N_NODES; i += gridDim.x*256){
    m1 = fmaxf(m1, s1[i]); m2 = fmaxf(m2, s2[i]);
  }
  #pragma unroll
  for(int off=32; off; off>>=1){
    m1 = fmaxf(m1, __shfl_down(m1,off));
    m2 = fmaxf(m2, __shfl_down(m2,off));
  }
  __shared__ float sm1[4], sm2[4];
  int lane = threadIdx.x&63, wid = threadIdx.x>>6;
  if(lane==0){ sm1[wid]=m1; sm2[wid]=m2; }
  __syncthreads();
  if(threadIdx.x==0){
    for(int w=1;w<4;w++){ m1=fmaxf(m1,sm1[w]); m2=fmaxf(m2,sm2[w]); }
    atomicMax(&scalU[0], encf(m1));
    atomicMax(&scalU[1], encf(m2));
  }
}

// ---- exp(logit - c) over E+N entries; store e<E; Z accumulated in double ----
__global__ __launch_bounds__(256) void k_logits(const int* __restrict__ row,
    const int* __restrict__ col, const float* __restrict__ s1,
    const float* __restrict__ s2, const unsigned* __restrict__ scalU,
    float* __restrict__ exbuf, double* __restrict__ Zp){
  float cc = decf(scalU[0]) + decf(scalU[1]);
  double zsum = 0.0;
  int total = N_EDGES + N_NODES;
  for(int e = blockIdx.x*256+threadIdx.x; e < total; e += gridDim.x*256){
    float l;
    if(e < N_EDGES) l = s1[row[e]] + s2[col[e]];
    else { int i = e - N_EDGES; l = s1[i] + s2[i]; }
    float ex = expf(l - cc);
    if(e < N_EDGES) exbuf[e] = ex;
    zsum += (double)ex;
  }
  #pragma unroll
  for(int off=32; off; off>>=1) zsum += __shfl_down(zsum, off);
  __shared__ double sz[4];
  int lane=threadIdx.x&63, wid=threadIdx.x>>6;
  if(lane==0) sz[wid]=zsum;
  __syncthreads();
  if(threadIdx.x==0){
    atomicAdd(Zp, sz[0]+sz[1]+sz[2]+sz[3]);
  }
}

// ---- edge MLP layer1 + relu + att-weight + scatter to u[row], avec[row] ----
__global__ __launch_bounds__(256) void k_edge(const int* __restrict__ row,
    const float* __restrict__ edge_attr, const float* __restrict__ We1,
    const float* __restrict__ be1, const float* __restrict__ exbuf,
    const double* __restrict__ Zp, float* __restrict__ u, float* __restrict__ avec){
  __shared__ float2 w1s[FE][64];
  __shared__ float2 b1s[64];
  int tid = threadIdx.x;
  #pragma unroll
  for(int p=0;p<8;p++){
    int q = tid + p*256;  // 0..2047
    int k = q >> 6, j = q & 63;
    w1s[k][j] = *(const float2*)&We1[k*128 + j*2];
  }
  if(tid < 64) b1s[tid] = *(const float2*)&be1[tid*2];
  __syncthreads();
  float invZ = (float)(1.0 / Zp[0]);
  int lane = tid & 63, wid = tid >> 6;
  for(int e = blockIdx.x*4 + wid; e < N_EDGES; e += gridDim.x*4){
    float eav = (lane < FE) ? edge_attr[e*FE + lane] : 0.f;
    float2 acc = b1s[lane];
    #pragma unroll
    for(int k=0;k<FE;k++){
      float w = __shfl(eav, k);
      float2 wv = w1s[k][lane];
      acc.x += w * wv.x;
      acc.y += w * wv.y;
    }
    float watt = exbuf[e] * invZ;
    float t0 = watt * fmaxf(acc.x, 0.f);
    float t1 = watt * fmaxf(acc.y, 0.f);
    int r = row[e];
    atomicAdd(&u[r*128 + lane*2],   t0);
    atomicAdd(&u[r*128 + lane*2+1], t1);
    if(lane == 0) atomicAdd(&avec[r], watt);
  }
}

// ---- conv2 epilogue + elu + pool scatter ----
__global__ __launch_bounds__(256) void k_pool(const float* __restrict__ accum,
    const float* __restrict__ xw, const float* __restrict__ dinv,
    const float* __restrict__ b2, const int* __restrict__ batch,
    float* __restrict__ sums, float* __restrict__ cntg){
  int lane = threadIdx.x & 63, wid = threadIdx.x >> 6;
  int i = blockIdx.x*4 + wid;
  if(i >= N_NODES) return;
  float di = dinv[i]; float sl = 2.f*di*di;
  float2 a  = *(const float2*)&accum[i*128+lane*2];
  float2 xv = *(const float2*)&xw[i*128+lane*2];
  float2 bb = *(const float2*)&b2[lane*2];
  float x0 = a.x + sl*xv.x + bb.x;
  float x1 = a.y + sl*xv.y + bb.y;
  float h0 = x0>0.f?x0:expm1f(x0);
  float h1 = x1>0.f?x1:expm1f(x1);
  int g = batch[i];
  atomicAdd(&sums[g*128+lane*2],   h0);
  atomicAdd(&sums[g*128+lane*2+1], h1);
  if(lane==0) atomicAdd(&cntg[g], 1.0f);
}

// ---- final: out[g] = (sums[g]@Wfc)/max(cnt,1) + bfc ----
__global__ __launch_bounds__(64) void k_final(const float* __restrict__ sums,
    const float* __restrict__ cntg, const float* __restrict__ Wfc,
    const float* __restrict__ bfc, float* __restrict__ out){
  int g = blockIdx.x;
  int lane = threadIdx.x;
  float v = sums[g*128+lane]*Wfc[lane] + sums[g*128+64+lane]*Wfc[64+lane];
  #pragma unroll
  for(int off=32; off; off>>=1) v += __shfl_down(v, off);
  if(lane==0){
    float c = fmaxf(cntg[g], 1.0f);
    out[g] = v / c + bfc[0];
  }
}

extern "C" void kernel_launch(void* const* d_in, const int* in_sizes, int n_in,
                              void* d_out, int out_size, void* d_ws, size_t ws_size,
                              hipStream_t stream) {
  (void)in_sizes; (void)n_in; (void)out_size; (void)ws_size;
  const float* x         = (const float*)d_in[0];
  const int*   edge_idx  = (const int*)d_in[1];
  const float* edge_attr = (const float*)d_in[2];
  const int*   batch     = (const int*)d_in[3];
  const float* W1  = (const float*)d_in[4];
  const float* b1  = (const float*)d_in[5];
  const float* W2  = (const float*)d_in[6];
  const float* b2  = (const float*)d_in[7];
  const float* We1 = (const float*)d_in[8];
  const float* be1 = (const float*)d_in[9];
  const float* We2 = (const float*)d_in[10];
  const float* be2 = (const float*)d_in[11];
  const float* Watt= (const float*)d_in[12];
  // d_in[13] = batt: cancels in softmax (logit - c), unused
  const float* Wfc = (const float*)d_in[14];
  const float* bfc = (const float*)d_in[15];
  float* out = (float*)d_out;

  const int* row = edge_idx;             // edge_index[0]
  const int* col = edge_idx + N_EDGES;   // edge_index[1]

  // workspace layout
  char* wsb = (char*)d_ws;
  double*   Zp    = (double*)wsb;
  unsigned* scalU = (unsigned*)(Zp + 1);
  float* base  = (float*)(scalU + 2);      // 16B offset
  float* cnt   = base;                     // N
  float* dinv  = cnt  + N_NODES;           // N
  float* s1    = dinv + N_NODES;           // N
  float* s2    = s1   + N_NODES;           // N
  float* avec  = s2   + N_NODES;           // N
  float* A     = avec + N_NODES;           // N*H (xw1 -> u -> xw2)
  float* B     = A + (size_t)N_NODES*H;    // N*H (conv accumulator)
  float* C     = B + (size_t)N_NODES*H;    // N*H (h / h2)
  float* exbuf = C + (size_t)N_NODES*H;    // E
  float* sums  = exbuf + N_EDGES;          // G*H
  float* cntg  = sums + GRAPHS*H;          // G

  const size_t NH = (size_t)N_NODES*H;

  hipMemsetAsync(d_ws, 0, 16, stream);                         // Zp, scalU
  hipMemsetAsync(cnt,  0, N_NODES*sizeof(float), stream);
  hipMemsetAsync(avec, 0, N_NODES*sizeof(float), stream);
  hipMemsetAsync(B,    0, NH*sizeof(float), stream);
  hipMemsetAsync(sums, 0, (GRAPHS*H+GRAPHS)*sizeof(float), stream);

  k_deg<<<(N_EDGES+255)/256, 256, 0, stream>>>(col, cnt);
  k_dinv<<<(N_NODES+255)/256, 256, 0, stream>>>(cnt, dinv);

  int gemmGrid = (N_NODES + 31)/32;
  // xw1 = x @ W1
  k_gemm<<<gemmGrid, 256, 0, stream>>>(x, W1, A, nullptr, nullptr, nullptr, N_NODES, 0);
  // conv1 scatter
  k_conv<<<(N_EDGES+3)/4, 256, 0, stream>>>(row, col, dinv, A, B);
  // h = elu(...), s1, s2
  k_elu_score<<<(N_NODES+3)/4, 256, 0, stream>>>(B, A, dinv, b1, Watt, C, s1, s2);
  // softmax stats
  k_maxred<<<120, 256, 0, stream>>>(s1, s2, scalU);
  k_logits<<<240, 256, 0, stream>>>(row, col, s1, s2, scalU, exbuf, Zp);
  // u accumulator (reuse A)
  hipMemsetAsync(A, 0, NH*sizeof(float), stream);
  k_edge<<<4096, 256, 0, stream>>>(row, edge_attr, We1, be1, exbuf, Zp, A, avec);
  // h2 = h + u@We2 + avec⊗be2 (in place on C)
  k_gemm<<<gemmGrid, 256, 0, stream>>>(A, We2, C, C, avec, be2, N_NODES, 1);
  // xw2 = h2 @ W2
  k_gemm<<<gemmGrid, 256, 0, stream>>>(C, W2, A, nullptr, nullptr, nullptr, N_NODES, 0);
  // conv2 scatter
  hipMemsetAsync(B, 0, NH*sizeof(float), stream);
  k_conv<<<(N_EDGES+3)/4, 256, 0, stream>>>(row, col, dinv, A, B);
  // pool
  k_pool<<<(N_NODES+3)/4, 256, 0, stream>>>(B, A, dinv, b2, batch, sums, cntg);
  k_final<<<GRAPHS, 64, 0, stream>>>(sums, cntg, Wfc, bfc, out);
}

// Round 2
// 1448.980 us; speedup vs baseline: 2.3828x; 2.3828x over previous
//
#include <hip/hip_runtime.h>
#include <math.h>

#define N_NODES 50000
#define N_EDGES 800000
#define FE 32
#define H 128
#define GRAPHS 64

__device__ inline unsigned encf(float f){
  unsigned u = __float_as_uint(f);
  return (u & 0x80000000u) ? ~u : (u | 0x80000000u);
}
__device__ inline float decf(unsigned u){
  unsigned b = (u & 0x80000000u) ? (u & 0x7fffffffu) : ~u;
  return __uint_as_float(b);
}

__device__ inline int wave_incl_scan(int v, int lane){
  #pragma unroll
  for(int o=1;o<64;o<<=1){ int t = __shfl_up(v,o); if(lane>=o) v += t; }
  return v;
}

// ---- CSR degree counts (int atomics) ----
__global__ __launch_bounds__(256) void k_count(const int* __restrict__ row,
    const int* __restrict__ col, int* __restrict__ rowCnt, int* __restrict__ colCnt){
  int e = blockIdx.x*256 + threadIdx.x;
  if(e < N_EDGES){
    atomicAdd(&rowCnt[row[e]], 1);
    atomicAdd(&colCnt[col[e]], 1);
  }
}

// ---- single-block exclusive scan: cnt[n] -> off[n+1], cur[n] (cnt may alias cur) ----
__global__ __launch_bounds__(1024) void k_scan(const int* cnt, int* off, int* cur, int n){
  __shared__ int wtot[16];
  __shared__ int btot;
  __shared__ int carry;
  int tid = threadIdx.x;
  int lane = tid & 63, wid = tid >> 6;
  if(tid == 0) carry = 0;
  for(int base = 0; base < n; base += 1024){
    int idx = base + tid;
    int v = (idx < n) ? cnt[idx] : 0;
    int incl = wave_incl_scan(v, lane);
    if(lane == 63) wtot[wid] = incl;
    __syncthreads();                       // (A) also orders prev carry write
    if(wid == 0){
      int wv = (lane < 16) ? wtot[lane] : 0;
      int wsum = wave_incl_scan(wv, lane);
      if(lane < 16) wtot[lane] = wsum - wv;  // exclusive wave offsets
      if(lane == 15) btot = wsum;            // chunk total
    }
    __syncthreads();                       // (B)
    int c0 = carry;
    int excl = c0 + wtot[wid] + incl - v;
    if(idx < n){ off[idx] = excl; cur[idx] = excl; }
    int bt = btot;
    __syncthreads();                       // (C)
    if(tid == 0) carry = c0 + bt;
  }
  __syncthreads();
  if(tid == 0) off[n] = carry;
}

// ---- scatter edge ids into CSR buckets ----
__global__ __launch_bounds__(256) void k_scatter(const int* __restrict__ row,
    const int* __restrict__ col, int* rowCur, int* colCur,
    int* __restrict__ permRow, int* __restrict__ permCol){
  int e = blockIdx.x*256 + threadIdx.x;
  if(e < N_EDGES){
    int p = atomicAdd(&rowCur[row[e]], 1); permRow[p] = e;
    int q = atomicAdd(&colCur[col[e]], 1); permCol[q] = e;
  }
}

__global__ __launch_bounds__(256) void k_dinv(const int* __restrict__ colOff, float* __restrict__ dinv){
  int i = blockIdx.x*256 + threadIdx.x;
  if(i < N_NODES){
    int deg = colOff[i+1] - colOff[i];
    dinv[i] = rsqrtf((float)deg + 2.0f);
  }
}

// ---- GEMM: out[M,128] = A[M,128] @ W[128,128]; mode 1: out = acc + addC + avec⊗bias ----
__global__ __launch_bounds__(256) void k_gemm(const float* __restrict__ A,
    const float* __restrict__ W, float* __restrict__ out,
    const float* __restrict__ addC, const float* __restrict__ avec,
    const float* __restrict__ bias, int M, int mode){
  __shared__ float As[32][33];
  __shared__ float Ws[32][128];
  int tid = threadIdx.x;
  int tx = tid & 127, ty = tid >> 7;
  int rowBase = blockIdx.x * 32;
  float acc[16];
  #pragma unroll
  for(int i=0;i<16;i++) acc[i]=0.f;
  for(int kc=0;kc<4;kc++){
    #pragma unroll
    for(int p=0;p<4;p++){
      int q = tid + p*256;
      int r = q >> 5, c = q & 31;
      int gr = rowBase + r;
      As[r][c] = (gr < M) ? A[gr*128 + kc*32 + c] : 0.f;
    }
    #pragma unroll
    for(int p=0;p<16;p++){
      int q = tid + p*256;
      int r = q >> 7, c = q & 127;
      Ws[r][c] = W[(kc*32+r)*128 + c];
    }
    __syncthreads();
    #pragma unroll
    for(int kk=0;kk<32;kk++){
      float w = Ws[kk][tx];
      #pragma unroll
      for(int rr=0;rr<16;rr++)
        acc[rr] += As[rr*2+ty][kk] * w;
    }
    __syncthreads();
  }
  #pragma unroll
  for(int rr=0;rr<16;rr++){
    int gr = rowBase + rr*2+ty;
    if(gr < M){
      float v = acc[rr];
      if(mode==1) v += addC[gr*128+tx] + avec[gr]*bias[tx];
      out[gr*128+tx] = v;
    }
  }
}

// ---- conv gather: out[c] = dinv[c] * sum_{e: col==c} dinv[row_e] * xw[row_e] ----
__global__ __launch_bounds__(256) void k_conv_g(const int* __restrict__ perm,
    const int* __restrict__ off, const int* __restrict__ src,
    const float* __restrict__ dinv, const float* __restrict__ xw,
    float* __restrict__ out){
  int lane = threadIdx.x & 63, wid = threadIdx.x >> 6;
  int node = blockIdx.x*4 + wid;
  if(node >= N_NODES) return;
  int lane2 = lane*2;
  int s = __builtin_amdgcn_readfirstlane(off[node]);
  int t = __builtin_amdgcn_readfirstlane(off[node+1]);
  float2 acc = make_float2(0.f, 0.f);
  int j = s;
  for(; j+1 < t; j += 2){
    int e0 = __builtin_amdgcn_readfirstlane(perm[j]);
    int e1 = __builtin_amdgcn_readfirstlane(perm[j+1]);
    int r0 = src[e0], r1 = src[e1];
    float n0 = dinv[r0], n1 = dinv[r1];
    float2 v0 = *(const float2*)&xw[(size_t)r0*H + lane2];
    float2 v1 = *(const float2*)&xw[(size_t)r1*H + lane2];
    acc.x = fmaf(n0, v0.x, acc.x); acc.y = fmaf(n0, v0.y, acc.y);
    acc.x = fmaf(n1, v1.x, acc.x); acc.y = fmaf(n1, v1.y, acc.y);
  }
  if(j < t){
    int e0 = __builtin_amdgcn_readfirstlane(perm[j]);
    int r0 = src[e0];
    float n0 = dinv[r0];
    float2 v0 = *(const float2*)&xw[(size_t)r0*H + lane2];
    acc.x = fmaf(n0, v0.x, acc.x); acc.y = fmaf(n0, v0.y, acc.y);
  }
  float dc = dinv[node];
  *(float2*)&out[(size_t)node*H + lane2] = make_float2(acc.x*dc, acc.y*dc);
}

// ---- h = elu(accum + 2*dinv^2*xw + b); s1 = h@Watt[:H], s2 = h@Watt[H:] ----
__global__ __launch_bounds__(256) void k_elu_score(const float* __restrict__ accum,
    const float* __restrict__ xw, const float* __restrict__ dinv,
    const float* __restrict__ b, const float* __restrict__ Watt,
    float* __restrict__ h, float* __restrict__ s1, float* __restrict__ s2){
  int lane = threadIdx.x & 63;
  int wid = threadIdx.x >> 6;
  int i = blockIdx.x*4 + wid;
  if(i >= N_NODES) return;
  float di = dinv[i]; float sl = 2.f*di*di;
  float2 a  = *(const float2*)&accum[(size_t)i*H+lane*2];
  float2 xv = *(const float2*)&xw[(size_t)i*H+lane*2];
  float2 bb = *(const float2*)&b[lane*2];
  float x0 = a.x + sl*xv.x + bb.x;
  float x1 = a.y + sl*xv.y + bb.y;
  float h0 = x0 > 0.f ? x0 : expm1f(x0);
  float h1 = x1 > 0.f ? x1 : expm1f(x1);
  *(float2*)&h[(size_t)i*H+lane*2] = make_float2(h0,h1);
  float2 w1 = *(const float2*)&Watt[lane*2];
  float2 w2 = *(const float2*)&Watt[H+lane*2];
  float p1 = h0*w1.x + h1*w1.y;
  float p2 = h0*w2.x + h1*w2.y;
  #pragma unroll
  for(int off=32; off; off>>=1){
    p1 += __shfl_down(p1, off);
    p2 += __shfl_down(p2, off);
  }
  if(lane==0){ s1[i]=p1; s2[i]=p2; }
}

// ---- max reduction of s1,s2 into encoded uints ----
__global__ __launch_bounds__(256) void k_maxred(const float* __restrict__ s1,
    const float* __restrict__ s2, unsigned* __restrict__ scalU){
  float m1 = -1e38f, m2 = -1e38f;
  for(int i = blockIdx.x*256+threadIdx.x; i < N_NODES; i += gridDim.x*256){
    m1 = fmaxf(m1, s1[i]); m2 = fmaxf(m2, s2[i]);
  }
  #pragma unroll
  for(int off=32; off; off>>=1){
    m1 = fmaxf(m1, __shfl_down(m1,off));
    m2 = fmaxf(m2, __shfl_down(m2,off));
  }
  __shared__ float sm1[4], sm2[4];
  int lane = threadIdx.x&63, wid = threadIdx.x>>6;
  if(lane==0){ sm1[wid]=m1; sm2[wid]=m2; }
  __syncthreads();
  if(threadIdx.x==0){
    for(int w=1;w<4;w++){ m1=fmaxf(m1,sm1[w]); m2=fmaxf(m2,sm2[w]); }
    atomicMax(&scalU[0], encf(m1));
    atomicMax(&scalU[1], encf(m2));
  }
}

// ---- exp(logit - c) over E+N entries; store e<E; Z accumulated in double ----
__global__ __launch_bounds__(256) void k_logits(const int* __restrict__ row,
    const int* __restrict__ col, const float* __restrict__ s1,
    const float* __restrict__ s2, const unsigned* __restrict__ scalU,
    float* __restrict__ exbuf, double* __restrict__ Zp){
  float cc = decf(scalU[0]) + decf(scalU[1]);
  double zsum = 0.0;
  int total = N_EDGES + N_NODES;
  for(int e = blockIdx.x*256+threadIdx.x; e < total; e += gridDim.x*256){
    float l;
    if(e < N_EDGES) l = s1[row[e]] + s2[col[e]];
    else { int i = e - N_EDGES; l = s1[i] + s2[i]; }
    float ex = expf(l - cc);
    if(e < N_EDGES) exbuf[e] = ex;
    zsum += (double)ex;
  }
  #pragma unroll
  for(int off=32; off; off>>=1) zsum += __shfl_down(zsum, off);
  __shared__ double sz[4];
  int lane=threadIdx.x&63, wid=threadIdx.x>>6;
  if(lane==0) sz[wid]=zsum;
  __syncthreads();
  if(threadIdx.x==0){
    atomicAdd(Zp, sz[0]+sz[1]+sz[2]+sz[3]);
  }
}

// ---- edge MLP + att weight, gathered per source node (no atomics) ----
__global__ __launch_bounds__(256) void k_edge_g(const int* __restrict__ permRow,
    const int* __restrict__ rowOff, const float* __restrict__ edge_attr,
    const float* __restrict__ We1, const float* __restrict__ be1,
    const float* __restrict__ exbuf, const double* __restrict__ Zp,
    float* __restrict__ u, float* __restrict__ avec){
  int lane = threadIdx.x & 63, wid = threadIdx.x >> 6;
  int node = blockIdx.x*4 + wid;
  if(node >= N_NODES) return;
  int lane2 = lane*2;
  // We1 column pair for this lane, held in registers (64 VGPRs)
  float2 wv[FE];
  #pragma unroll
  for(int k=0;k<FE;k++) wv[k] = *(const float2*)&We1[k*H + lane2];
  float2 bb = *(const float2*)&be1[lane2];
  float invZ = (float)(1.0 / Zp[0]);
  int s = __builtin_amdgcn_readfirstlane(rowOff[node]);
  int t = __builtin_amdgcn_readfirstlane(rowOff[node+1]);
  float2 uacc = make_float2(0.f, 0.f);
  float aacc = 0.f;
  for(int j=s; j<t; j++){
    int e = __builtin_amdgcn_readfirstlane(permRow[j]);
    const float* ea = edge_attr + (size_t)e*FE;   // uniform address -> scalar loads
    float watt = exbuf[e] * invZ;
    float2 acc = bb;
    #pragma unroll
    for(int k=0;k<FE;k++){
      float w = ea[k];
      acc.x = fmaf(w, wv[k].x, acc.x);
      acc.y = fmaf(w, wv[k].y, acc.y);
    }
    uacc.x = fmaf(watt, fmaxf(acc.x, 0.f), uacc.x);
    uacc.y = fmaf(watt, fmaxf(acc.y, 0.f), uacc.y);
    aacc += watt;
  }
  *(float2*)&u[(size_t)node*H + lane2] = uacc;
  if(lane==0) avec[node] = aacc;
}

// ---- per-graph segment starts (batch is sorted) ----
__global__ __launch_bounds__(256) void k_starts(const int* __restrict__ batch, int* __restrict__ starts){
  int i = blockIdx.x*256 + threadIdx.x;
  if(i >= N_NODES) return;
  int b = batch[i];
  if(i == 0){ for(int g=0; g<=b; g++) starts[g] = 0; }
  else { int pb = batch[i-1]; for(int g=pb+1; g<=b; g++) starts[g] = i; }
  if(i == N_NODES-1){ for(int g=b+1; g<=GRAPHS; g++) starts[g] = N_NODES; }
}

// ---- conv2 epilogue + elu + segment-sum pool (few atomics) ----
__global__ __launch_bounds__(256) void k_pool_g(const float* __restrict__ accum,
    const float* __restrict__ xw, const float* __restrict__ dinv,
    const float* __restrict__ b2, const int* __restrict__ starts,
    float* __restrict__ sums){
  int g = blockIdx.x;
  int s = starts[g], t = starts[g+1];
  int len = t - s;
  int chunk = (len + 7) >> 3;
  int i0 = s + blockIdx.y * chunk;
  int i1 = min(t, i0 + chunk);
  int tid = threadIdx.x;
  int f = tid & 127, half = tid >> 7;
  float acc = 0.f;
  for(int i = i0 + half; i < i1; i += 2){
    float di = dinv[i]; float sl = 2.f*di*di;
    float x = accum[(size_t)i*H + f] + sl*xw[(size_t)i*H + f] + b2[f];
    acc += (x > 0.f) ? x : expm1f(x);
  }
  __shared__ float red[256];
  red[tid] = acc;
  __syncthreads();
  if(tid < 128){
    float v = red[tid] + red[tid + 128];
    atomicAdd(&sums[g*H + tid], v);
  }
}

// ---- final: out[g] = (sums[g]@Wfc)/max(cnt,1) + bfc ----
__global__ __launch_bounds__(64) void k_final(const float* __restrict__ sums,
    const int* __restrict__ starts, const float* __restrict__ Wfc,
    const float* __restrict__ bfc, float* __restrict__ out){
  int g = blockIdx.x;
  int lane = threadIdx.x;
  float v = sums[g*H+lane]*Wfc[lane] + sums[g*H+64+lane]*Wfc[64+lane];
  #pragma unroll
  for(int off=32; off; off>>=1) v += __shfl_down(v, off);
  if(lane==0){
    int c = starts[g+1] - starts[g];
    float cf = (float)(c > 1 ? c : 1);
    out[g] = v / cf + bfc[0];
  }
}

extern "C" void kernel_launch(void* const* d_in, const int* in_sizes, int n_in,
                              void* d_out, int out_size, void* d_ws, size_t ws_size,
                              hipStream_t stream) {
  (void)in_sizes; (void)n_in; (void)out_size; (void)ws_size;
  const float* x         = (const float*)d_in[0];
  const int*   edge_idx  = (const int*)d_in[1];
  const float* edge_attr = (const float*)d_in[2];
  const int*   batch     = (const int*)d_in[3];
  const float* W1  = (const float*)d_in[4];
  const float* b1  = (const float*)d_in[5];
  const float* W2  = (const float*)d_in[6];
  const float* b2  = (const float*)d_in[7];
  const float* We1 = (const float*)d_in[8];
  const float* be1 = (const float*)d_in[9];
  const float* We2 = (const float*)d_in[10];
  const float* be2 = (const float*)d_in[11];
  const float* Watt= (const float*)d_in[12];
  // d_in[13] = batt: cancels in softmax (logit - c), unused
  const float* Wfc = (const float*)d_in[14];
  const float* bfc = (const float*)d_in[15];
  float* out = (float*)d_out;

  const int* row = edge_idx;             // edge_index[0]
  const int* col = edge_idx + N_EDGES;   // edge_index[1]

  // ---- workspace layout (16B-aligned regions) ----
  char* wsb = (char*)d_ws;
  size_t curOff = 0;
  auto alloc = [&](size_t bytes)->char*{
    char* p = wsb + curOff;
    curOff = (curOff + bytes + 15) & ~(size_t)15;
    return p;
  };
  double*   Zp     = (double*)alloc(16);
  unsigned* scalU  = (unsigned*)(Zp + 1);
  int* rowOffA = (int*)alloc((N_NODES+1)*4);
  int* rowCurA = (int*)alloc(N_NODES*4);
  int* colOffA = (int*)alloc((N_NODES+1)*4);
  int* colCurA = (int*)alloc(N_NODES*4);
  int* permRow = (int*)alloc((size_t)N_EDGES*4);
  int* permCol = (int*)alloc((size_t)N_EDGES*4);
  int* starts  = (int*)alloc((GRAPHS+1)*4);
  float* dinv  = (float*)alloc(N_NODES*4);
  float* s1    = (float*)alloc(N_NODES*4);
  float* s2    = (float*)alloc(N_NODES*4);
  float* avec  = (float*)alloc(N_NODES*4);
  const size_t NH = (size_t)N_NODES*H;
  float* A     = (float*)alloc(NH*4);   // xw1 -> u -> xw2
  float* B     = (float*)alloc(NH*4);   // conv accumulator
  float* C     = (float*)alloc(NH*4);   // h / h2
  float* exbuf = (float*)alloc((size_t)N_EDGES*4);
  float* sums  = (float*)alloc(GRAPHS*H*4);

  // ---- zeroing (small) ----
  hipMemsetAsync(Zp, 0, 16, stream);
  hipMemsetAsync(rowCurA, 0, N_NODES*4, stream);
  hipMemsetAsync(colCurA, 0, N_NODES*4, stream);
  hipMemsetAsync(sums, 0, GRAPHS*H*4, stream);

  // ---- CSR build ----
  k_count<<<(N_EDGES+255)/256, 256, 0, stream>>>(row, col, rowCurA, colCurA);
  k_scan<<<1, 1024, 0, stream>>>(rowCurA, rowOffA, rowCurA, N_NODES);
  k_scan<<<1, 1024, 0, stream>>>(colCurA, colOffA, colCurA, N_NODES);
  k_scatter<<<(N_EDGES+255)/256, 256, 0, stream>>>(row, col, rowCurA, colCurA, permRow, permCol);
  k_dinv<<<(N_NODES+255)/256, 256, 0, stream>>>(colOffA, dinv);

  int gemmGrid = (N_NODES + 31)/32;
  int nodeGrid = (N_NODES + 3)/4;
  // xw1 = x @ W1
  k_gemm<<<gemmGrid, 256, 0, stream>>>(x, W1, A, nullptr, nullptr, nullptr, N_NODES, 0);
  // conv1 gather
  k_conv_g<<<nodeGrid, 256, 0, stream>>>(permCol, colOffA, row, dinv, A, B);
  // h = elu(...), s1, s2
  k_elu_score<<<nodeGrid, 256, 0, stream>>>(B, A, dinv, b1, Watt, C, s1, s2);
  // softmax stats
  k_maxred<<<120, 256, 0, stream>>>(s1, s2, scalU);
  k_logits<<<240, 256, 0, stream>>>(row, col, s1, s2, scalU, exbuf, Zp);
  // u (into A) + avec, gathered (no atomics, full overwrite)
  k_edge_g<<<nodeGrid, 256, 0, stream>>>(permRow, rowOffA, edge_attr, We1, be1, exbuf, Zp, A, avec);
  // h2 = h + u@We2 + avec⊗be2 (in place on C)
  k_gemm<<<gemmGrid, 256, 0, stream>>>(A, We2, C, C, avec, be2, N_NODES, 1);
  // xw2 = h2 @ W2
  k_gemm<<<gemmGrid, 256, 0, stream>>>(C, W2, A, nullptr, nullptr, nullptr, N_NODES, 0);
  // conv2 gather
  k_conv_g<<<nodeGrid, 256, 0, stream>>>(permCol, colOffA, row, dinv, A, B);
  // pool
  k_starts<<<(N_NODES+255)/256, 256, 0, stream>>>(batch, starts);
  k_pool_g<<<dim3(GRAPHS, 8), 256, 0, stream>>>(B, A, dinv, b2, starts, sums);
  k_final<<<GRAPHS, 64, 0, stream>>>(sums, starts, Wfc, bfc, out);
}

// Round 3
// 939.425 us; speedup vs baseline: 3.6753x; 1.5424x over previous
//
#include <hip/hip_runtime.h>
#include <math.h>

#define N_NODES 50000
#define N_EDGES 800000
#define FE 32
#define H 128
#define GRAPHS 64

__device__ inline unsigned encf(float f){
  unsigned u = __float_as_uint(f);
  return (u & 0x80000000u) ? ~u : (u | 0x80000000u);
}
__device__ inline float decf(unsigned u){
  unsigned b = (u & 0x80000000u) ? (u & 0x7fffffffu) : ~u;
  return __uint_as_float(b);
}

__device__ inline int wave_incl_scan(int v, int lane){
  #pragma unroll
  for(int o=1;o<64;o<<=1){ int t = __shfl_up(v,o); if(lane>=o) v += t; }
  return v;
}

// ---- CSR degree counts (int atomics) ----
__global__ __launch_bounds__(256) void k_count(const int* __restrict__ row,
    const int* __restrict__ col, int* __restrict__ rowCnt, int* __restrict__ colCnt){
  int e = blockIdx.x*256 + threadIdx.x;
  if(e < N_EDGES){
    atomicAdd(&rowCnt[row[e]], 1);
    atomicAdd(&colCnt[col[e]], 1);
  }
}

// ---- exclusive scan, 2 independent arrays (block 0: A, block 1: B) ----
__global__ __launch_bounds__(1024) void k_scan2(int* cntA, int* offA, int* curA,
    int* cntB, int* offB, int* curB, int n){
  int* cnt = blockIdx.x ? cntB : cntA;
  int* off = blockIdx.x ? offB : offA;
  int* cur = blockIdx.x ? curB : curA;
  __shared__ int wtot[16];
  __shared__ int btot;
  __shared__ int carry;
  int tid = threadIdx.x;
  int lane = tid & 63, wid = tid >> 6;
  if(tid == 0) carry = 0;
  for(int base = 0; base < n; base += 1024){
    int idx = base + tid;
    int v = (idx < n) ? cnt[idx] : 0;
    int incl = wave_incl_scan(v, lane);
    if(lane == 63) wtot[wid] = incl;
    __syncthreads();
    if(wid == 0){
      int wv = (lane < 16) ? wtot[lane] : 0;
      int wsum = wave_incl_scan(wv, lane);
      if(lane < 16) wtot[lane] = wsum - wv;
      if(lane == 15) btot = wsum;
    }
    __syncthreads();
    int c0 = carry;
    int excl = c0 + wtot[wid] + incl - v;
    if(idx < n){ off[idx] = excl; cur[idx] = excl; }
    int bt = btot;
    __syncthreads();
    if(tid == 0) carry = c0 + bt;
  }
  __syncthreads();
  if(tid == 0) off[n] = carry;
}

// ---- scatter edge ids into CSR buckets ----
__global__ __launch_bounds__(256) void k_scatter(const int* __restrict__ row,
    const int* __restrict__ col, int* rowCur, int* colCur,
    int* __restrict__ permRow, int* __restrict__ permCol){
  int e = blockIdx.x*256 + threadIdx.x;
  if(e < N_EDGES){
    int p = atomicAdd(&rowCur[row[e]], 1); permRow[p] = e;
    int q = atomicAdd(&colCur[col[e]], 1); permCol[q] = e;
  }
}

__global__ __launch_bounds__(256) void k_dinv(const int* __restrict__ colOff, float* __restrict__ dinv){
  int i = blockIdx.x*256 + threadIdx.x;
  if(i < N_NODES){
    int deg = colOff[i+1] - colOff[i];
    dinv[i] = rsqrtf((float)deg + 2.0f);
  }
}

// ---- GEMM: out[M,128] = A[M,128] @ W[128,128]; mode 1: out += addC + avec⊗bias ----
// 64-row block tile, full-K A tile in LDS (b128 reads), W staged per 32-k chunk.
// Thread tile 8 rows x 4 cols, k unrolled 4-wide: 12 ds_read_b128 per 128 FMAs.
__global__ __launch_bounds__(256) void k_gemm(const float* __restrict__ A,
    const float* __restrict__ W, float* __restrict__ out,
    const float* __restrict__ addC, const float* __restrict__ avec,
    const float* __restrict__ bias, int M, int mode){
  __shared__ float As[64][132];
  __shared__ float Ws[32][128];
  int tid = threadIdx.x;
  int tx = tid & 31, ty = tid >> 5;       // tx: col group (4 cols), ty: row group (8 rows)
  int rowBase = blockIdx.x * 64;
  // stage full A tile (64 rows x 128 k)
  #pragma unroll
  for(int p=0;p<8;p++){
    int idx = tid + p*256;                // 0..2047 float4 slots
    int r = idx >> 5, c4 = idx & 31;
    int gr = rowBase + r;
    float4 v = make_float4(0.f,0.f,0.f,0.f);
    if(gr < M) v = *(const float4*)&A[(size_t)gr*128 + c4*4];
    *(float4*)&As[r][c4*4] = v;
  }
  float4 acc[8];
  #pragma unroll
  for(int r=0;r<8;r++) acc[r] = make_float4(0.f,0.f,0.f,0.f);
  for(int kc=0;kc<4;kc++){
    #pragma unroll
    for(int p=0;p<4;p++){
      int idx = tid + p*256;              // 0..1023 float4 slots
      int r = idx >> 5, c4 = idx & 31;
      *(float4*)&Ws[r][c4*4] = *(const float4*)&W[(size_t)(kc*32+r)*128 + c4*4];
    }
    __syncthreads();
    #pragma unroll
    for(int kk4=0;kk4<8;kk4++){
      int kbase = kc*32 + kk4*4;
      float4 b0 = *(const float4*)&Ws[kk4*4+0][tx*4];
      float4 b1 = *(const float4*)&Ws[kk4*4+1][tx*4];
      float4 b2 = *(const float4*)&Ws[kk4*4+2][tx*4];
      float4 b3 = *(const float4*)&Ws[kk4*4+3][tx*4];
      #pragma unroll
      for(int r=0;r<8;r++){
        float4 a = *(const float4*)&As[ty*8+r][kbase];
        acc[r].x = fmaf(a.x, b0.x, acc[r].x);
        acc[r].y = fmaf(a.x, b0.y, acc[r].y);
        acc[r].z = fmaf(a.x, b0.z, acc[r].z);
        acc[r].w = fmaf(a.x, b0.w, acc[r].w);
        acc[r].x = fmaf(a.y, b1.x, acc[r].x);
        acc[r].y = fmaf(a.y, b1.y, acc[r].y);
        acc[r].z = fmaf(a.y, b1.z, acc[r].z);
        acc[r].w = fmaf(a.y, b1.w, acc[r].w);
        acc[r].x = fmaf(a.z, b2.x, acc[r].x);
        acc[r].y = fmaf(a.z, b2.y, acc[r].y);
        acc[r].z = fmaf(a.z, b2.z, acc[r].z);
        acc[r].w = fmaf(a.z, b2.w, acc[r].w);
        acc[r].x = fmaf(a.w, b3.x, acc[r].x);
        acc[r].y = fmaf(a.w, b3.y, acc[r].y);
        acc[r].z = fmaf(a.w, b3.z, acc[r].z);
        acc[r].w = fmaf(a.w, b3.w, acc[r].w);
      }
    }
    __syncthreads();
  }
  #pragma unroll
  for(int r=0;r<8;r++){
    int gr = rowBase + ty*8 + r;
    if(gr < M){
      float4 v = acc[r];
      if(mode==1){
        float4 c = *(const float4*)&addC[(size_t)gr*128 + tx*4];
        float4 bb = *(const float4*)&bias[tx*4];
        float av = avec[gr];
        v.x += c.x + av*bb.x;
        v.y += c.y + av*bb.y;
        v.z += c.z + av*bb.z;
        v.w += c.w + av*bb.w;
      }
      *(float4*)&out[(size_t)gr*128 + tx*4] = v;
    }
  }
}

// ---- conv gather: out[c] = dinv[c] * sum_{e: col==c} dinv[row_e] * xw[row_e] ----
__global__ __launch_bounds__(256) void k_conv_g(const int* __restrict__ perm,
    const int* __restrict__ off, const int* __restrict__ src,
    const float* __restrict__ dinv, const float* __restrict__ xw,
    float* __restrict__ out){
  int lane = threadIdx.x & 63, wid = threadIdx.x >> 6;
  int node = blockIdx.x*4 + wid;
  if(node >= N_NODES) return;
  int lane2 = lane*2;
  int s = __builtin_amdgcn_readfirstlane(off[node]);
  int t = __builtin_amdgcn_readfirstlane(off[node+1]);
  float2 acc = make_float2(0.f, 0.f);
  int j = s;
  for(; j+1 < t; j += 2){
    int e0 = __builtin_amdgcn_readfirstlane(perm[j]);
    int e1 = __builtin_amdgcn_readfirstlane(perm[j+1]);
    int r0 = src[e0], r1 = src[e1];
    float n0 = dinv[r0], n1 = dinv[r1];
    float2 v0 = *(const float2*)&xw[(size_t)r0*H + lane2];
    float2 v1 = *(const float2*)&xw[(size_t)r1*H + lane2];
    acc.x = fmaf(n0, v0.x, acc.x); acc.y = fmaf(n0, v0.y, acc.y);
    acc.x = fmaf(n1, v1.x, acc.x); acc.y = fmaf(n1, v1.y, acc.y);
  }
  if(j < t){
    int e0 = __builtin_amdgcn_readfirstlane(perm[j]);
    int r0 = src[e0];
    float n0 = dinv[r0];
    float2 v0 = *(const float2*)&xw[(size_t)r0*H + lane2];
    acc.x = fmaf(n0, v0.x, acc.x); acc.y = fmaf(n0, v0.y, acc.y);
  }
  float dc = dinv[node];
  *(float2*)&out[(size_t)node*H + lane2] = make_float2(acc.x*dc, acc.y*dc);
}

// ---- h = elu(accum + 2*dinv^2*xw + b); s1 = h@Watt[:H], s2 = h@Watt[H:] ----
__global__ __launch_bounds__(256) void k_elu_score(const float* __restrict__ accum,
    const float* __restrict__ xw, const float* __restrict__ dinv,
    const float* __restrict__ b, const float* __restrict__ Watt,
    float* __restrict__ h, float* __restrict__ s1, float* __restrict__ s2){
  int lane = threadIdx.x & 63;
  int wid = threadIdx.x >> 6;
  int i = blockIdx.x*4 + wid;
  if(i >= N_NODES) return;
  float di = dinv[i]; float sl = 2.f*di*di;
  float2 a  = *(const float2*)&accum[(size_t)i*H+lane*2];
  float2 xv = *(const float2*)&xw[(size_t)i*H+lane*2];
  float2 bb = *(const float2*)&b[lane*2];
  float x0 = a.x + sl*xv.x + bb.x;
  float x1 = a.y + sl*xv.y + bb.y;
  float h0 = x0 > 0.f ? x0 : expm1f(x0);
  float h1 = x1 > 0.f ? x1 : expm1f(x1);
  *(float2*)&h[(size_t)i*H+lane*2] = make_float2(h0,h1);
  float2 w1 = *(const float2*)&Watt[lane*2];
  float2 w2 = *(const float2*)&Watt[H+lane*2];
  float p1 = h0*w1.x + h1*w1.y;
  float p2 = h0*w2.x + h1*w2.y;
  #pragma unroll
  for(int off=32; off; off>>=1){
    p1 += __shfl_down(p1, off);
    p2 += __shfl_down(p2, off);
  }
  if(lane==0){ s1[i]=p1; s2[i]=p2; }
}

// ---- max reduction of s1,s2 into encoded uints ----
__global__ __launch_bounds__(256) void k_maxred(const float* __restrict__ s1,
    const float* __restrict__ s2, unsigned* __restrict__ scalU){
  float m1 = -1e38f, m2 = -1e38f;
  for(int i = blockIdx.x*256+threadIdx.x; i < N_NODES; i += gridDim.x*256){
    m1 = fmaxf(m1, s1[i]); m2 = fmaxf(m2, s2[i]);
  }
  #pragma unroll
  for(int off=32; off; off>>=1){
    m1 = fmaxf(m1, __shfl_down(m1,off));
    m2 = fmaxf(m2, __shfl_down(m2,off));
  }
  __shared__ float sm1[4], sm2[4];
  int lane = threadIdx.x&63, wid = threadIdx.x>>6;
  if(lane==0){ sm1[wid]=m1; sm2[wid]=m2; }
  __syncthreads();
  if(threadIdx.x==0){
    for(int w=1;w<4;w++){ m1=fmaxf(m1,sm1[w]); m2=fmaxf(m2,sm2[w]); }
    atomicMax(&scalU[0], encf(m1));
    atomicMax(&scalU[1], encf(m2));
  }
}

// ---- exp(logit - c) over E+N entries; store e<E; Z accumulated in double ----
__global__ __launch_bounds__(256) void k_logits(const int* __restrict__ row,
    const int* __restrict__ col, const float* __restrict__ s1,
    const float* __restrict__ s2, const unsigned* __restrict__ scalU,
    float* __restrict__ exbuf, double* __restrict__ Zp){
  float cc = decf(scalU[0]) + decf(scalU[1]);
  double zsum = 0.0;
  int total = N_EDGES + N_NODES;
  for(int e = blockIdx.x*256+threadIdx.x; e < total; e += gridDim.x*256){
    float l;
    if(e < N_EDGES) l = s1[row[e]] + s2[col[e]];
    else { int i = e - N_EDGES; l = s1[i] + s2[i]; }
    float ex = expf(l - cc);
    if(e < N_EDGES) exbuf[e] = ex;
    zsum += (double)ex;
  }
  #pragma unroll
  for(int off=32; off; off>>=1) zsum += __shfl_down(zsum, off);
  __shared__ double sz[4];
  int lane=threadIdx.x&63, wid=threadIdx.x>>6;
  if(lane==0) sz[wid]=zsum;
  __syncthreads();
  if(threadIdx.x==0){
    atomicAdd(Zp, sz[0]+sz[1]+sz[2]+sz[3]);
  }
}

// ---- edge MLP + att weight, gathered per source node (no atomics) ----
__global__ __launch_bounds__(256) void k_edge_g(const int* __restrict__ permRow,
    const int* __restrict__ rowOff, const float* __restrict__ edge_attr,
    const float* __restrict__ We1, const float* __restrict__ be1,
    const float* __restrict__ exbuf, const double* __restrict__ Zp,
    float* __restrict__ u, float* __restrict__ avec){
  int lane = threadIdx.x & 63, wid = threadIdx.x >> 6;
  int node = blockIdx.x*4 + wid;
  if(node >= N_NODES) return;
  int lane2 = lane*2;
  float2 wv[FE];
  #pragma unroll
  for(int k=0;k<FE;k++) wv[k] = *(const float2*)&We1[k*H + lane2];
  float2 bb = *(const float2*)&be1[lane2];
  float invZ = (float)(1.0 / Zp[0]);
  int s = __builtin_amdgcn_readfirstlane(rowOff[node]);
  int t = __builtin_amdgcn_readfirstlane(rowOff[node+1]);
  float2 uacc = make_float2(0.f, 0.f);
  float aacc = 0.f;
  for(int j=s; j<t; j++){
    int e = __builtin_amdgcn_readfirstlane(permRow[j]);
    const float* ea = edge_attr + (size_t)e*FE;
    float watt = exbuf[e] * invZ;
    float2 acc = bb;
    #pragma unroll
    for(int k=0;k<FE;k++){
      float w = ea[k];
      acc.x = fmaf(w, wv[k].x, acc.x);
      acc.y = fmaf(w, wv[k].y, acc.y);
    }
    uacc.x = fmaf(watt, fmaxf(acc.x, 0.f), uacc.x);
    uacc.y = fmaf(watt, fmaxf(acc.y, 0.f), uacc.y);
    aacc += watt;
  }
  *(float2*)&u[(size_t)node*H + lane2] = uacc;
  if(lane==0) avec[node] = aacc;
}

// ---- per-graph segment starts (batch is sorted) ----
__global__ __launch_bounds__(256) void k_starts(const int* __restrict__ batch, int* __restrict__ starts){
  int i = blockIdx.x*256 + threadIdx.x;
  if(i >= N_NODES) return;
  int b = batch[i];
  if(i == 0){ for(int g=0; g<=b; g++) starts[g] = 0; }
  else { int pb = batch[i-1]; for(int g=pb+1; g<=b; g++) starts[g] = i; }
  if(i == N_NODES-1){ for(int g=b+1; g<=GRAPHS; g++) starts[g] = N_NODES; }
}

// ---- conv2 epilogue + elu + segment-sum pool (few atomics) ----
__global__ __launch_bounds__(256) void k_pool_g(const float* __restrict__ accum,
    const float* __restrict__ xw, const float* __restrict__ dinv,
    const float* __restrict__ b2, const int* __restrict__ starts,
    float* __restrict__ sums){
  int g = blockIdx.x;
  int s = starts[g], t = starts[g+1];
  int len = t - s;
  int chunk = (len + 7) >> 3;
  int i0 = s + blockIdx.y * chunk;
  int i1 = min(t, i0 + chunk);
  int tid = threadIdx.x;
  int f = tid & 127, half = tid >> 7;
  float acc = 0.f;
  for(int i = i0 + half; i < i1; i += 2){
    float di = dinv[i]; float sl = 2.f*di*di;
    float x = accum[(size_t)i*H + f] + sl*xw[(size_t)i*H + f] + b2[f];
    acc += (x > 0.f) ? x : expm1f(x);
  }
  __shared__ float red[256];
  red[tid] = acc;
  __syncthreads();
  if(tid < 128){
    float v = red[tid] + red[tid + 128];
    atomicAdd(&sums[g*H + tid], v);
  }
}

// ---- final: out[g] = (sums[g]@Wfc)/max(cnt,1) + bfc ----
__global__ __launch_bounds__(64) void k_final(const float* __restrict__ sums,
    const int* __restrict__ starts, const float* __restrict__ Wfc,
    const float* __restrict__ bfc, float* __restrict__ out){
  int g = blockIdx.x;
  int lane = threadIdx.x;
  float v = sums[g*H+lane]*Wfc[lane] + sums[g*H+64+lane]*Wfc[64+lane];
  #pragma unroll
  for(int off=32; off; off>>=1) v += __shfl_down(v, off);
  if(lane==0){
    int c = starts[g+1] - starts[g];
    float cf = (float)(c > 1 ? c : 1);
    out[g] = v / cf + bfc[0];
  }
}

extern "C" void kernel_launch(void* const* d_in, const int* in_sizes, int n_in,
                              void* d_out, int out_size, void* d_ws, size_t ws_size,
                              hipStream_t stream) {
  (void)in_sizes; (void)n_in; (void)out_size; (void)ws_size;
  const float* x         = (const float*)d_in[0];
  const int*   edge_idx  = (const int*)d_in[1];
  const float* edge_attr = (const float*)d_in[2];
  const int*   batch     = (const int*)d_in[3];
  const float* W1  = (const float*)d_in[4];
  const float* b1  = (const float*)d_in[5];
  const float* W2  = (const float*)d_in[6];
  const float* b2  = (const float*)d_in[7];
  const float* We1 = (const float*)d_in[8];
  const float* be1 = (const float*)d_in[9];
  const float* We2 = (const float*)d_in[10];
  const float* be2 = (const float*)d_in[11];
  const float* Watt= (const float*)d_in[12];
  // d_in[13] = batt: cancels in softmax (logit - c), unused
  const float* Wfc = (const float*)d_in[14];
  const float* bfc = (const float*)d_in[15];
  float* out = (float*)d_out;

  const int* row = edge_idx;             // edge_index[0]
  const int* col = edge_idx + N_EDGES;   // edge_index[1]

  // ---- workspace layout (16B-aligned regions) ----
  char* wsb = (char*)d_ws;
  size_t curOff = 0;
  auto alloc = [&](size_t bytes)->char*{
    char* p = wsb + curOff;
    curOff = (curOff + bytes + 15) & ~(size_t)15;
    return p;
  };
  double*   Zp     = (double*)alloc(16);
  unsigned* scalU  = (unsigned*)(Zp + 1);
  int* rowOffA = (int*)alloc((N_NODES+1)*4);
  int* rowCurA = (int*)alloc(N_NODES*4);
  int* colOffA = (int*)alloc((N_NODES+1)*4);
  int* colCurA = (int*)alloc(N_NODES*4);
  int* permRow = (int*)alloc((size_t)N_EDGES*4);
  int* permCol = (int*)alloc((size_t)N_EDGES*4);
  int* starts  = (int*)alloc((GRAPHS+1)*4);
  float* dinv  = (float*)alloc(N_NODES*4);
  float* s1    = (float*)alloc(N_NODES*4);
  float* s2    = (float*)alloc(N_NODES*4);
  float* avec  = (float*)alloc(N_NODES*4);
  const size_t NH = (size_t)N_NODES*H;
  float* A     = (float*)alloc(NH*4);   // xw1 -> u -> xw2
  float* B     = (float*)alloc(NH*4);   // conv accumulator
  float* C     = (float*)alloc(NH*4);   // h / h2
  float* exbuf = (float*)alloc((size_t)N_EDGES*4);
  float* sums  = (float*)alloc(GRAPHS*H*4);

  // ---- zeroing (small) ----
  hipMemsetAsync(Zp, 0, 16, stream);
  hipMemsetAsync(rowCurA, 0, N_NODES*4, stream);
  hipMemsetAsync(colCurA, 0, N_NODES*4, stream);
  hipMemsetAsync(sums, 0, GRAPHS*H*4, stream);

  // ---- CSR build ----
  k_count<<<(N_EDGES+255)/256, 256, 0, stream>>>(row, col, rowCurA, colCurA);
  k_scan2<<<2, 1024, 0, stream>>>(rowCurA, rowOffA, rowCurA, colCurA, colOffA, colCurA, N_NODES);
  k_scatter<<<(N_EDGES+255)/256, 256, 0, stream>>>(row, col, rowCurA, colCurA, permRow, permCol);
  k_dinv<<<(N_NODES+255)/256, 256, 0, stream>>>(colOffA, dinv);

  int gemmGrid = (N_NODES + 63)/64;
  int nodeGrid = (N_NODES + 3)/4;
  // xw1 = x @ W1
  k_gemm<<<gemmGrid, 256, 0, stream>>>(x, W1, A, nullptr, nullptr, nullptr, N_NODES, 0);
  // conv1 gather
  k_conv_g<<<nodeGrid, 256, 0, stream>>>(permCol, colOffA, row, dinv, A, B);
  // h = elu(...), s1, s2
  k_elu_score<<<nodeGrid, 256, 0, stream>>>(B, A, dinv, b1, Watt, C, s1, s2);
  // softmax stats
  k_maxred<<<120, 256, 0, stream>>>(s1, s2, scalU);
  k_logits<<<240, 256, 0, stream>>>(row, col, s1, s2, scalU, exbuf, Zp);
  // u (into A) + avec, gathered (no atomics, full overwrite)
  k_edge_g<<<nodeGrid, 256, 0, stream>>>(permRow, rowOffA, edge_attr, We1, be1, exbuf, Zp, A, avec);
  // h2 = h + u@We2 + avec⊗be2 (in place on C)
  k_gemm<<<gemmGrid, 256, 0, stream>>>(A, We2, C, C, avec, be2, N_NODES, 1);
  // xw2 = h2 @ W2
  k_gemm<<<gemmGrid, 256, 0, stream>>>(C, W2, A, nullptr, nullptr, nullptr, N_NODES, 0);
  // conv2 gather
  k_conv_g<<<nodeGrid, 256, 0, stream>>>(permCol, colOffA, row, dinv, A, B);
  // pool
  k_starts<<<(N_NODES+255)/256, 256, 0, stream>>>(batch, starts);
  k_pool_g<<<dim3(GRAPHS, 8), 256, 0, stream>>>(B, A, dinv, b2, starts, sums);
  k_final<<<GRAPHS, 64, 0, stream>>>(sums, starts, Wfc, bfc, out);
}

// Round 4
// 927.585 us; speedup vs baseline: 3.7222x; 1.0128x over previous
//
#include <hip/hip_runtime.h>
#include <math.h>

#define N_NODES 50000
#define N_EDGES 800000
#define FE 32
#define H 128
#define GRAPHS 64

__device__ inline unsigned encf(float f){
  unsigned u = __float_as_uint(f);
  return (u & 0x80000000u) ? ~u : (u | 0x80000000u);
}
__device__ inline float decf(unsigned u){
  unsigned b = (u & 0x80000000u) ? (u & 0x7fffffffu) : ~u;
  return __uint_as_float(b);
}

__device__ inline int wave_incl_scan(int v, int lane){
  #pragma unroll
  for(int o=1;o<64;o<<=1){ int t = __shfl_up(v,o); if(lane>=o) v += t; }
  return v;
}

// ---- CSR degree counts (int atomics) ----
__global__ __launch_bounds__(256) void k_count(const int* __restrict__ row,
    const int* __restrict__ col, int* __restrict__ rowCnt, int* __restrict__ colCnt){
  int e = blockIdx.x*256 + threadIdx.x;
  if(e < N_EDGES){
    atomicAdd(&rowCnt[row[e]], 1);
    atomicAdd(&colCnt[col[e]], 1);
  }
}

// ---- exclusive scan, 2 independent arrays (block 0: A, block 1: B), 4 elems/thread ----
__global__ __launch_bounds__(1024) void k_scan2(int* cntA, int* offA, int* curA,
    int* cntB, int* offB, int* curB, int n){
  int* cnt = blockIdx.x ? cntB : cntA;
  int* off = blockIdx.x ? offB : offA;
  int* cur = blockIdx.x ? curB : curA;
  __shared__ int wtot[16];
  __shared__ int btot;
  __shared__ int carry;
  int tid = threadIdx.x;
  int lane = tid & 63, wid = tid >> 6;
  if(tid == 0) carry = 0;
  for(int base = 0; base < n; base += 4096){
    int i0 = base + tid*4;
    int4 v = make_int4(0,0,0,0);
    if(i0+3 < n) v = *(const int4*)&cnt[i0];
    else {
      if(i0   < n) v.x = cnt[i0];
      if(i0+1 < n) v.y = cnt[i0+1];
      if(i0+2 < n) v.z = cnt[i0+2];
      if(i0+3 < n) v.w = cnt[i0+3];
    }
    int sum = v.x+v.y+v.z+v.w;
    int incl = wave_incl_scan(sum, lane);
    if(lane == 63) wtot[wid] = incl;
    __syncthreads();                      // (A)
    if(wid == 0){
      int wv = (lane < 16) ? wtot[lane] : 0;
      int wsum = wave_incl_scan(wv, lane);
      if(lane < 16) wtot[lane] = wsum - wv;
      if(lane == 15) btot = wsum;
    }
    __syncthreads();                      // (B)
    int c0 = carry;
    int e0 = c0 + wtot[wid] + incl - sum;
    int e1 = e0 + v.x, e2 = e1 + v.y, e3 = e2 + v.z;
    if(i0   < n){ off[i0]   = e0; cur[i0]   = e0; }
    if(i0+1 < n){ off[i0+1] = e1; cur[i0+1] = e1; }
    if(i0+2 < n){ off[i0+2] = e2; cur[i0+2] = e2; }
    if(i0+3 < n){ off[i0+3] = e3; cur[i0+3] = e3; }
    int bt = btot;
    __syncthreads();                      // (C)
    if(tid == 0) carry = c0 + bt;
  }
  __syncthreads();
  if(tid == 0) off[n] = carry;
}

// ---- scatter edge ids into CSR buckets ----
__global__ __launch_bounds__(256) void k_scatter(const int* __restrict__ row,
    const int* __restrict__ col, int* rowCur, int* colCur,
    int* __restrict__ permRow, int* __restrict__ permCol){
  int e = blockIdx.x*256 + threadIdx.x;
  if(e < N_EDGES){
    int p = atomicAdd(&rowCur[row[e]], 1); permRow[p] = e;
    int q = atomicAdd(&colCur[col[e]], 1); permCol[q] = e;
  }
}

__global__ __launch_bounds__(256) void k_dinv(const int* __restrict__ colOff, float* __restrict__ dinv){
  int i = blockIdx.x*256 + threadIdx.x;
  if(i < N_NODES){
    int deg = colOff[i+1] - colOff[i];
    dinv[i] = rsqrtf((float)deg + 2.0f);
  }
}

// ---- GEMM: out[M,128] = A[M,128] @ W[128,128]; mode 1: out += addC + avec⊗bias ----
__global__ __launch_bounds__(256) void k_gemm(const float* __restrict__ A,
    const float* __restrict__ W, float* __restrict__ out,
    const float* __restrict__ addC, const float* __restrict__ avec,
    const float* __restrict__ bias, int M, int mode){
  __shared__ float As[64][132];
  __shared__ float Ws[32][128];
  int tid = threadIdx.x;
  int tx = tid & 31, ty = tid >> 5;
  int rowBase = blockIdx.x * 64;
  #pragma unroll
  for(int p=0;p<8;p++){
    int idx = tid + p*256;
    int r = idx >> 5, c4 = idx & 31;
    int gr = rowBase + r;
    float4 v = make_float4(0.f,0.f,0.f,0.f);
    if(gr < M) v = *(const float4*)&A[(size_t)gr*128 + c4*4];
    *(float4*)&As[r][c4*4] = v;
  }
  float4 acc[8];
  #pragma unroll
  for(int r=0;r<8;r++) acc[r] = make_float4(0.f,0.f,0.f,0.f);
  for(int kc=0;kc<4;kc++){
    #pragma unroll
    for(int p=0;p<4;p++){
      int idx = tid + p*256;
      int r = idx >> 5, c4 = idx & 31;
      *(float4*)&Ws[r][c4*4] = *(const float4*)&W[(size_t)(kc*32+r)*128 + c4*4];
    }
    __syncthreads();
    #pragma unroll
    for(int kk4=0;kk4<8;kk4++){
      int kbase = kc*32 + kk4*4;
      float4 b0 = *(const float4*)&Ws[kk4*4+0][tx*4];
      float4 b1 = *(const float4*)&Ws[kk4*4+1][tx*4];
      float4 b2 = *(const float4*)&Ws[kk4*4+2][tx*4];
      float4 b3 = *(const float4*)&Ws[kk4*4+3][tx*4];
      #pragma unroll
      for(int r=0;r<8;r++){
        float4 a = *(const float4*)&As[ty*8+r][kbase];
        acc[r].x = fmaf(a.x, b0.x, acc[r].x);
        acc[r].y = fmaf(a.x, b0.y, acc[r].y);
        acc[r].z = fmaf(a.x, b0.z, acc[r].z);
        acc[r].w = fmaf(a.x, b0.w, acc[r].w);
        acc[r].x = fmaf(a.y, b1.x, acc[r].x);
        acc[r].y = fmaf(a.y, b1.y, acc[r].y);
        acc[r].z = fmaf(a.y, b1.z, acc[r].z);
        acc[r].w = fmaf(a.y, b1.w, acc[r].w);
        acc[r].x = fmaf(a.z, b2.x, acc[r].x);
        acc[r].y = fmaf(a.z, b2.y, acc[r].y);
        acc[r].z = fmaf(a.z, b2.z, acc[r].z);
        acc[r].w = fmaf(a.z, b2.w, acc[r].w);
        acc[r].x = fmaf(a.w, b3.x, acc[r].x);
        acc[r].y = fmaf(a.w, b3.y, acc[r].y);
        acc[r].z = fmaf(a.w, b3.z, acc[r].z);
        acc[r].w = fmaf(a.w, b3.w, acc[r].w);
      }
    }
    __syncthreads();
  }
  #pragma unroll
  for(int r=0;r<8;r++){
    int gr = rowBase + ty*8 + r;
    if(gr < M){
      float4 v = acc[r];
      if(mode==1){
        float4 c = *(const float4*)&addC[(size_t)gr*128 + tx*4];
        float4 bb = *(const float4*)&bias[tx*4];
        float av = avec[gr];
        v.x += c.x + av*bb.x;
        v.y += c.y + av*bb.y;
        v.z += c.z + av*bb.z;
        v.w += c.w + av*bb.w;
      }
      *(float4*)&out[(size_t)gr*128 + tx*4] = v;
    }
  }
}

// ---- conv gather: out[c] = dinv[c] * sum_{e: col==c} dinv[row_e] * xw[row_e] ----
__global__ __launch_bounds__(256) void k_conv_g(const int* __restrict__ perm,
    const int* __restrict__ off, const int* __restrict__ src,
    const float* __restrict__ dinv, const float* __restrict__ xw,
    float* __restrict__ out){
  int lane = threadIdx.x & 63, wid = threadIdx.x >> 6;
  int node = blockIdx.x*4 + wid;
  if(node >= N_NODES) return;
  int lane2 = lane*2;
  int s = __builtin_amdgcn_readfirstlane(off[node]);
  int t = __builtin_amdgcn_readfirstlane(off[node+1]);
  float2 acc = make_float2(0.f, 0.f);
  float2 accB = make_float2(0.f, 0.f);
  int j = s;
  for(; j+3 < t; j += 4){
    int e0 = __builtin_amdgcn_readfirstlane(perm[j]);
    int e1 = __builtin_amdgcn_readfirstlane(perm[j+1]);
    int e2 = __builtin_amdgcn_readfirstlane(perm[j+2]);
    int e3 = __builtin_amdgcn_readfirstlane(perm[j+3]);
    int r0 = src[e0], r1 = src[e1], r2 = src[e2], r3 = src[e3];
    float n0 = dinv[r0], n1 = dinv[r1], n2 = dinv[r2], n3 = dinv[r3];
    float2 v0 = *(const float2*)&xw[(size_t)r0*H + lane2];
    float2 v1 = *(const float2*)&xw[(size_t)r1*H + lane2];
    float2 v2 = *(const float2*)&xw[(size_t)r2*H + lane2];
    float2 v3 = *(const float2*)&xw[(size_t)r3*H + lane2];
    acc.x  = fmaf(n0, v0.x, acc.x);  acc.y  = fmaf(n0, v0.y, acc.y);
    accB.x = fmaf(n1, v1.x, accB.x); accB.y = fmaf(n1, v1.y, accB.y);
    acc.x  = fmaf(n2, v2.x, acc.x);  acc.y  = fmaf(n2, v2.y, acc.y);
    accB.x = fmaf(n3, v3.x, accB.x); accB.y = fmaf(n3, v3.y, accB.y);
  }
  for(; j < t; j++){
    int e0 = __builtin_amdgcn_readfirstlane(perm[j]);
    int r0 = src[e0];
    float n0 = dinv[r0];
    float2 v0 = *(const float2*)&xw[(size_t)r0*H + lane2];
    acc.x = fmaf(n0, v0.x, acc.x); acc.y = fmaf(n0, v0.y, acc.y);
  }
  acc.x += accB.x; acc.y += accB.y;
  float dc = dinv[node];
  *(float2*)&out[(size_t)node*H + lane2] = make_float2(acc.x*dc, acc.y*dc);
}

// ---- h = elu(accum + 2*dinv^2*xw + b); s1 = h@Watt[:H], s2 = h@Watt[H:] ----
__global__ __launch_bounds__(256) void k_elu_score(const float* __restrict__ accum,
    const float* __restrict__ xw, const float* __restrict__ dinv,
    const float* __restrict__ b, const float* __restrict__ Watt,
    float* __restrict__ h, float* __restrict__ s1, float* __restrict__ s2){
  int lane = threadIdx.x & 63;
  int wid = threadIdx.x >> 6;
  int i = blockIdx.x*4 + wid;
  if(i >= N_NODES) return;
  float di = dinv[i]; float sl = 2.f*di*di;
  float2 a  = *(const float2*)&accum[(size_t)i*H+lane*2];
  float2 xv = *(const float2*)&xw[(size_t)i*H+lane*2];
  float2 bb = *(const float2*)&b[lane*2];
  float x0 = a.x + sl*xv.x + bb.x;
  float x1 = a.y + sl*xv.y + bb.y;
  float h0 = x0 > 0.f ? x0 : expm1f(x0);
  float h1 = x1 > 0.f ? x1 : expm1f(x1);
  *(float2*)&h[(size_t)i*H+lane*2] = make_float2(h0,h1);
  float2 w1 = *(const float2*)&Watt[lane*2];
  float2 w2 = *(const float2*)&Watt[H+lane*2];
  float p1 = h0*w1.x + h1*w1.y;
  float p2 = h0*w2.x + h1*w2.y;
  #pragma unroll
  for(int off=32; off; off>>=1){
    p1 += __shfl_down(p1, off);
    p2 += __shfl_down(p2, off);
  }
  if(lane==0){ s1[i]=p1; s2[i]=p2; }
}

// ---- max reduction of s1,s2 into encoded uints ----
__global__ __launch_bounds__(256) void k_maxred(const float* __restrict__ s1,
    const float* __restrict__ s2, unsigned* __restrict__ scalU){
  float m1 = -1e38f, m2 = -1e38f;
  for(int i = blockIdx.x*256+threadIdx.x; i < N_NODES; i += gridDim.x*256){
    m1 = fmaxf(m1, s1[i]); m2 = fmaxf(m2, s2[i]);
  }
  #pragma unroll
  for(int off=32; off; off>>=1){
    m1 = fmaxf(m1, __shfl_down(m1,off));
    m2 = fmaxf(m2, __shfl_down(m2,off));
  }
  __shared__ float sm1[4], sm2[4];
  int lane = threadIdx.x&63, wid = threadIdx.x>>6;
  if(lane==0){ sm1[wid]=m1; sm2[wid]=m2; }
  __syncthreads();
  if(threadIdx.x==0){
    for(int w=1;w<4;w++){ m1=fmaxf(m1,sm1[w]); m2=fmaxf(m2,sm2[w]); }
    atomicMax(&scalU[0], encf(m1));
    atomicMax(&scalU[1], encf(m2));
  }
}

// ---- exp(logit - c) over E+N entries; store e<E; Z accumulated in double ----
__global__ __launch_bounds__(256) void k_logits(const int* __restrict__ row,
    const int* __restrict__ col, const float* __restrict__ s1,
    const float* __restrict__ s2, const unsigned* __restrict__ scalU,
    float* __restrict__ exbuf, double* __restrict__ Zp){
  float cc = decf(scalU[0]) + decf(scalU[1]);
  double zsum = 0.0;
  int total = N_EDGES + N_NODES;
  for(int e = blockIdx.x*256+threadIdx.x; e < total; e += gridDim.x*256){
    float l;
    if(e < N_EDGES) l = s1[row[e]] + s2[col[e]];
    else { int i = e - N_EDGES; l = s1[i] + s2[i]; }
    float ex = expf(l - cc);
    if(e < N_EDGES) exbuf[e] = ex;
    zsum += (double)ex;
  }
  #pragma unroll
  for(int off=32; off; off>>=1) zsum += __shfl_down(zsum, off);
  __shared__ double sz[4];
  int lane=threadIdx.x&63, wid=threadIdx.x>>6;
  if(lane==0) sz[wid]=zsum;
  __syncthreads();
  if(threadIdx.x==0){
    atomicAdd(Zp, sz[0]+sz[1]+sz[2]+sz[3]);
  }
}

// ---- edge MLP + att weight, gathered per source node (no atomics) ----
// __launch_bounds__(256,4): 128-VGPR budget so wv[32] float2 stays resident.
__global__ __launch_bounds__(256, 4) void k_edge_g(const int* __restrict__ permRow,
    const int* __restrict__ rowOff, const float* __restrict__ edge_attr,
    const float* __restrict__ We1, const float* __restrict__ be1,
    const float* __restrict__ exbuf, const double* __restrict__ Zp,
    float* __restrict__ u, float* __restrict__ avec){
  int lane = threadIdx.x & 63, wid = threadIdx.x >> 6;
  int node = blockIdx.x*4 + wid;
  if(node >= N_NODES) return;
  int lane2 = lane*2;
  float2 wv[FE];
  #pragma unroll
  for(int k=0;k<FE;k++) wv[k] = *(const float2*)&We1[k*H + lane2];
  float2 bb = *(const float2*)&be1[lane2];
  float invZ = (float)(1.0 / Zp[0]);
  int s = __builtin_amdgcn_readfirstlane(rowOff[node]);
  int t = __builtin_amdgcn_readfirstlane(rowOff[node+1]);
  float2 uacc  = make_float2(0.f, 0.f);
  float2 uaccB = make_float2(0.f, 0.f);
  float aacc = 0.f;
  int j = s;
  for(; j+1 < t; j += 2){
    int e0 = __builtin_amdgcn_readfirstlane(permRow[j]);
    int e1 = __builtin_amdgcn_readfirstlane(permRow[j+1]);
    const float* ea0 = edge_attr + (size_t)e0*FE;
    const float* ea1 = edge_attr + (size_t)e1*FE;
    float w0 = exbuf[e0]*invZ;
    float w1 = exbuf[e1]*invZ;
    float2 acc0 = bb, acc1 = bb;
    #pragma unroll
    for(int k=0;k<FE;k++){
      float a0 = ea0[k];
      float a1 = ea1[k];
      acc0.x = fmaf(a0, wv[k].x, acc0.x);
      acc0.y = fmaf(a0, wv[k].y, acc0.y);
      acc1.x = fmaf(a1, wv[k].x, acc1.x);
      acc1.y = fmaf(a1, wv[k].y, acc1.y);
    }
    uacc.x  = fmaf(w0, fmaxf(acc0.x, 0.f), uacc.x);
    uacc.y  = fmaf(w0, fmaxf(acc0.y, 0.f), uacc.y);
    uaccB.x = fmaf(w1, fmaxf(acc1.x, 0.f), uaccB.x);
    uaccB.y = fmaf(w1, fmaxf(acc1.y, 0.f), uaccB.y);
    aacc += w0 + w1;
  }
  if(j < t){
    int e0 = __builtin_amdgcn_readfirstlane(permRow[j]);
    const float* ea0 = edge_attr + (size_t)e0*FE;
    float w0 = exbuf[e0]*invZ;
    float2 acc0 = bb;
    #pragma unroll
    for(int k=0;k<FE;k++){
      float a0 = ea0[k];
      acc0.x = fmaf(a0, wv[k].x, acc0.x);
      acc0.y = fmaf(a0, wv[k].y, acc0.y);
    }
    uacc.x = fmaf(w0, fmaxf(acc0.x, 0.f), uacc.x);
    uacc.y = fmaf(w0, fmaxf(acc0.y, 0.f), uacc.y);
    aacc += w0;
  }
  uacc.x += uaccB.x; uacc.y += uaccB.y;
  *(float2*)&u[(size_t)node*H + lane2] = uacc;
  if(lane==0) avec[node] = aacc;
}

// ---- per-graph segment starts (batch is sorted) ----
__global__ __launch_bounds__(256) void k_starts(const int* __restrict__ batch, int* __restrict__ starts){
  int i = blockIdx.x*256 + threadIdx.x;
  if(i >= N_NODES) return;
  int b = batch[i];
  if(i == 0){ for(int g=0; g<=b; g++) starts[g] = 0; }
  else { int pb = batch[i-1]; for(int g=pb+1; g<=b; g++) starts[g] = i; }
  if(i == N_NODES-1){ for(int g=b+1; g<=GRAPHS; g++) starts[g] = N_NODES; }
}

// ---- conv2 epilogue + elu + segment-sum pool (few atomics) ----
__global__ __launch_bounds__(256) void k_pool_g(const float* __restrict__ accum,
    const float* __restrict__ xw, const float* __restrict__ dinv,
    const float* __restrict__ b2, const int* __restrict__ starts,
    float* __restrict__ sums){
  int g = blockIdx.x;
  int s = starts[g], t = starts[g+1];
  int len = t - s;
  int chunk = (len + 7) >> 3;
  int i0 = s + blockIdx.y * chunk;
  int i1 = min(t, i0 + chunk);
  int tid = threadIdx.x;
  int f = tid & 127, half = tid >> 7;
  float acc = 0.f;
  for(int i = i0 + half; i < i1; i += 2){
    float di = dinv[i]; float sl = 2.f*di*di;
    float x = accum[(size_t)i*H + f] + sl*xw[(size_t)i*H + f] + b2[f];
    acc += (x > 0.f) ? x : expm1f(x);
  }
  __shared__ float red[256];
  red[tid] = acc;
  __syncthreads();
  if(tid < 128){
    float v = red[tid] + red[tid + 128];
    atomicAdd(&sums[g*H + tid], v);
  }
}

// ---- final: out[g] = (sums[g]@Wfc)/max(cnt,1) + bfc ----
__global__ __launch_bounds__(64) void k_final(const float* __restrict__ sums,
    const int* __restrict__ starts, const float* __restrict__ Wfc,
    const float* __restrict__ bfc, float* __restrict__ out){
  int g = blockIdx.x;
  int lane = threadIdx.x;
  float v = sums[g*H+lane]*Wfc[lane] + sums[g*H+64+lane]*Wfc[64+lane];
  #pragma unroll
  for(int off=32; off; off>>=1) v += __shfl_down(v, off);
  if(lane==0){
    int c = starts[g+1] - starts[g];
    float cf = (float)(c > 1 ? c : 1);
    out[g] = v / cf + bfc[0];
  }
}

extern "C" void kernel_launch(void* const* d_in, const int* in_sizes, int n_in,
                              void* d_out, int out_size, void* d_ws, size_t ws_size,
                              hipStream_t stream) {
  (void)in_sizes; (void)n_in; (void)out_size; (void)ws_size;
  const float* x         = (const float*)d_in[0];
  const int*   edge_idx  = (const int*)d_in[1];
  const float* edge_attr = (const float*)d_in[2];
  const int*   batch     = (const int*)d_in[3];
  const float* W1  = (const float*)d_in[4];
  const float* b1  = (const float*)d_in[5];
  const float* W2  = (const float*)d_in[6];
  const float* b2  = (const float*)d_in[7];
  const float* We1 = (const float*)d_in[8];
  const float* be1 = (const float*)d_in[9];
  const float* We2 = (const float*)d_in[10];
  const float* be2 = (const float*)d_in[11];
  const float* Watt= (const float*)d_in[12];
  // d_in[13] = batt: cancels in softmax (logit - c), unused
  const float* Wfc = (const float*)d_in[14];
  const float* bfc = (const float*)d_in[15];
  float* out = (float*)d_out;

  const int* row = edge_idx;             // edge_index[0]
  const int* col = edge_idx + N_EDGES;   // edge_index[1]

  // ---- workspace layout (16B-aligned regions) ----
  char* wsb = (char*)d_ws;
  size_t curOff = 0;
  auto alloc = [&](size_t bytes)->char*{
    char* p = wsb + curOff;
    curOff = (curOff + bytes + 15) & ~(size_t)15;
    return p;
  };
  double*   Zp     = (double*)alloc(16);
  unsigned* scalU  = (unsigned*)(Zp + 1);
  int* rowOffA = (int*)alloc((N_NODES+1)*4);
  int* rowCurA = (int*)alloc(N_NODES*4);
  int* colOffA = (int*)alloc((N_NODES+1)*4);
  int* colCurA = (int*)alloc(N_NODES*4);
  int* permRow = (int*)alloc((size_t)N_EDGES*4);
  int* permCol = (int*)alloc((size_t)N_EDGES*4);
  int* starts  = (int*)alloc((GRAPHS+1)*4);
  float* dinv  = (float*)alloc(N_NODES*4);
  float* s1    = (float*)alloc(N_NODES*4);
  float* s2    = (float*)alloc(N_NODES*4);
  float* avec  = (float*)alloc(N_NODES*4);
  const size_t NH = (size_t)N_NODES*H;
  float* A     = (float*)alloc(NH*4);   // xw1 -> u -> xw2
  float* B     = (float*)alloc(NH*4);   // conv accumulator
  float* C     = (float*)alloc(NH*4);   // h / h2
  float* exbuf = (float*)alloc((size_t)N_EDGES*4);
  float* sums  = (float*)alloc(GRAPHS*H*4);

  // ---- zeroing (small) ----
  hipMemsetAsync(Zp, 0, 16, stream);
  hipMemsetAsync(rowCurA, 0, N_NODES*4, stream);
  hipMemsetAsync(colCurA, 0, N_NODES*4, stream);
  hipMemsetAsync(sums, 0, GRAPHS*H*4, stream);

  // ---- CSR build ----
  k_count<<<(N_EDGES+255)/256, 256, 0, stream>>>(row, col, rowCurA, colCurA);
  k_scan2<<<2, 1024, 0, stream>>>(rowCurA, rowOffA, rowCurA, colCurA, colOffA, colCurA, N_NODES);
  k_scatter<<<(N_EDGES+255)/256, 256, 0, stream>>>(row, col, rowCurA, colCurA, permRow, permCol);
  k_dinv<<<(N_NODES+255)/256, 256, 0, stream>>>(colOffA, dinv);

  int gemmGrid = (N_NODES + 63)/64;
  int nodeGrid = (N_NODES + 3)/4;
  // xw1 = x @ W1
  k_gemm<<<gemmGrid, 256, 0, stream>>>(x, W1, A, nullptr, nullptr, nullptr, N_NODES, 0);
  // conv1 gather
  k_conv_g<<<nodeGrid, 256, 0, stream>>>(permCol, colOffA, row, dinv, A, B);
  // h = elu(...), s1, s2
  k_elu_score<<<nodeGrid, 256, 0, stream>>>(B, A, dinv, b1, Watt, C, s1, s2);
  // softmax stats
  k_maxred<<<120, 256, 0, stream>>>(s1, s2, scalU);
  k_logits<<<240, 256, 0, stream>>>(row, col, s1, s2, scalU, exbuf, Zp);
  // u (into A) + avec, gathered (no atomics, full overwrite)
  k_edge_g<<<nodeGrid, 256, 0, stream>>>(permRow, rowOffA, edge_attr, We1, be1, exbuf, Zp, A, avec);
  // h2 = h + u@We2 + avec⊗be2 (in place on C)
  k_gemm<<<gemmGrid, 256, 0, stream>>>(A, We2, C, C, avec, be2, N_NODES, 1);
  // xw2 = h2 @ W2
  k_gemm<<<gemmGrid, 256, 0, stream>>>(C, W2, A, nullptr, nullptr, nullptr, N_NODES, 0);
  // conv2 gather
  k_conv_g<<<nodeGrid, 256, 0, stream>>>(permCol, colOffA, row, dinv, A, B);
  // pool
  k_starts<<<(N_NODES+255)/256, 256, 0, stream>>>(batch, starts);
  k_pool_g<<<dim3(GRAPHS, 8), 256, 0, stream>>>(B, A, dinv, b2, starts, sums);
  k_final<<<GRAPHS, 64, 0, stream>>>(sums, starts, Wfc, bfc, out);
}